// Round 8
// baseline (411.833 us; speedup 1.0000x reference)
//
#include <hip/hip_runtime.h>
#include <hip/hip_bf16.h>
#include <stdint.h>

#define NSP 16384   // 128*128 spatial
#define BATCH 4
#define EPSV 1e-6f

typedef __attribute__((ext_vector_type(8))) short fragAB;   // 8 bf16
typedef __attribute__((ext_vector_type(4))) float fragC;    // 4 fp32

__device__ __forceinline__ unsigned short f2bf(float f) {
    union { float f; unsigned u; } un; un.f = f;
    unsigned r = un.u + 0x7fffu + ((un.u >> 16) & 1u);   // RNE
    return (unsigned short)(r >> 16);
}

__device__ __forceinline__ float bf2f(unsigned u) {
    union { unsigned u; float f; } x; x.u = u << 16; return x.f;
}

#define GLD_LDS(g, l) __builtin_amdgcn_global_load_lds( \
    (const __attribute__((address_space(1))) void*)(g), \
    (__attribute__((address_space(3))) void*)(l), 16, 0, 0)

// XOR-swizzled fragment read: element (row m, colgroup g) at
// (m>>3)*512 + (m&7)*64 + ((g ^ (m&7))*8); matches global_load_lds lane slots.
__device__ __forceinline__ fragAB ldfrag(const unsigned short* ls, int m, int g) {
    return *(const fragAB*)&ls[((m >> 3) << 9) + ((m & 7) << 6) + ((g ^ (m & 7)) << 3)];
}

// Transposed q/k chunk tile [ch][n=128] bf16, XOR-swizzled: group g of row ch
// lives at slot (g ^ (ch&7)). Row stride 128 shorts (256 B).
__device__ __forceinline__ int tidx(int ch, int g) {
    return (ch << 7) + ((g ^ (ch & 7)) << 3);
}

// ---------------- fused: x transpose (blocks 0..8191) + weight prep (8192..8767) ----------------
__global__ __launch_bounds__(256) void transpose_prep(
    const float* __restrict__ x, unsigned short* __restrict__ xt,
    const float* __restrict__ wqkv, unsigned short* __restrict__ wqb,
    unsigned short* __restrict__ wvT) {
    __shared__ float lds[64 * 65];
    const int blk = blockIdx.x;
    const int t   = threadIdx.x;
    if (blk < 8192) {
        // ---- transpose_x: x (B,C,N) fp32 -> xt (B,N,C) bf16 ----
        const int b  = blk >> 11;
        const int c0 = ((blk >> 8) & 7) * 64;
        const int n0 = (blk & 255) * 64;
        const int nl = (t & 15) * 4;
        const int cl = t >> 4;
#pragma unroll
        for (int i = 0; i < 4; ++i) {
            int c = cl + i * 16;
            float4 v = *(const float4*)&x[((size_t)(b * 512 + c0 + c)) * NSP + n0 + nl];
            float* row = &lds[c * 65 + nl];
            row[0] = v.x; row[1] = v.y; row[2] = v.z; row[3] = v.w;
        }
        __syncthreads();
#pragma unroll
        for (int i = 0; i < 2; ++i) {
            int ch = t + i * 256;      // 0..511
            int n  = ch >> 3;
            int co = (ch & 7) * 8;
            unsigned v0, v1, v2, v3;
            v0 = f2bf(lds[(co + 0) * 65 + n]) | ((unsigned)f2bf(lds[(co + 1) * 65 + n]) << 16);
            v1 = f2bf(lds[(co + 2) * 65 + n]) | ((unsigned)f2bf(lds[(co + 3) * 65 + n]) << 16);
            v2 = f2bf(lds[(co + 4) * 65 + n]) | ((unsigned)f2bf(lds[(co + 5) * 65 + n]) << 16);
            v3 = f2bf(lds[(co + 6) * 65 + n]) | ((unsigned)f2bf(lds[(co + 7) * 65 + n]) << 16);
            uint4 pk; pk.x = v0; pk.y = v1; pk.z = v2; pk.w = v3;
            *(uint4*)&xt[((size_t)(b * NSP + n0 + n)) * 512 + c0 + co] = pk;
        }
        return;
    }
    const int pblk = blk - 8192;
    if (pblk < 512) {
        // ---- wqkv rows 0..1023 -> bf16 ----
        int i = (pblk * 256 + t) * 4;
        float4 v = *(const float4*)&wqkv[i];
        uint2 pk;
        pk.x = f2bf(v.x) | ((unsigned)f2bf(v.y) << 16);
        pk.y = f2bf(v.z) | ((unsigned)f2bf(v.w) << 16);
        *(uint2*)&wqb[i] = pk;
        return;
    }
    // ---- wv rows -> wvT (transposed, bf16) ----
    const int c0  = ((pblk - 512) & 7) * 64;
    const int ch0 = ((pblk - 512) >> 3) * 64;
    const int cl  = (t & 15) * 4;
    const int rl  = t >> 4;
#pragma unroll
    for (int i = 0; i < 4; ++i) {
        int r = rl + i * 16;   // ch row
        float4 v = *(const float4*)&wqkv[((size_t)(1024 + ch0 + r)) * 512 + c0 + cl];
        float* row = &lds[r * 65 + cl];
        row[0] = v.x; row[1] = v.y; row[2] = v.z; row[3] = v.w;
    }
    __syncthreads();
#pragma unroll
    for (int i = 0; i < 2; ++i) {
        int idx = t + i * 256;
        int c = idx >> 3;
        int g = (idx & 7) * 8;
        unsigned v0, v1, v2, v3;
        v0 = f2bf(lds[(g + 0) * 65 + c]) | ((unsigned)f2bf(lds[(g + 1) * 65 + c]) << 16);
        v1 = f2bf(lds[(g + 2) * 65 + c]) | ((unsigned)f2bf(lds[(g + 3) * 65 + c]) << 16);
        v2 = f2bf(lds[(g + 4) * 65 + c]) | ((unsigned)f2bf(lds[(g + 5) * 65 + c]) << 16);
        v3 = f2bf(lds[(g + 6) * 65 + c]) | ((unsigned)f2bf(lds[(g + 7) * 65 + c]) << 16);
        uint4 pk; pk.x = v0; pk.y = v1; pk.z = v2; pk.w = v3;
        *(uint4*)&wvT[((size_t)(c0 + c)) * 512 + ch0 + g] = pk;
    }
}

// ---------------- fused q/k GEMM + kq partial reduction ----------------
// GEMM phase = r4 non-spilling shape. kq tail r8: r4's UNSWAPPED MFMA order
// (mfma(Kt,Qt), which ran at 81us) + bf16 packed lane-linear stores (keeps
// r7's traffic halving). Slot map: wn*2048 + dt*1024 + mt*256 + ln*4 + r
// holds kq[c = mt*16+(ln>>4)*4+r][d = wn*32+dt*16+(ln&15)].
__global__ __launch_bounds__(256, 2) void gemm_qk_kq(
    const unsigned short* __restrict__ xt, const unsigned short* __restrict__ wq,
    const float* __restrict__ bqkv, unsigned short* __restrict__ partb) {
    __shared__ unsigned short S[(128 + 256) * 64];   // Als @0 (16KB), Bls @8192 (32KB)
    __shared__ unsigned short Qt[128 * 128];          // 32KB
    unsigned short* Bls = &S[8192];
    unsigned short* Kt  = &S[0];                      // alias: dead during staging, live after

    const int b  = blockIdx.z;
    const int hc = blockIdx.y;                        // head-pair chunk 0..3
    const int bx = blockIdx.x;
    const int n0 = bx * 128;
    const int t  = threadIdx.x;
    const int wv = t >> 6, ln = t & 63;
    const unsigned short* Ag = xt + (size_t)(b * NSP + n0) * 512;
    const int srow = ln >> 3;
    const int scol = ((ln & 7) ^ srow) << 3;
    const int isK = wv >> 1;                          // waves 2,3 -> k-channels
    unsigned short* T = isK ? Kt : Qt;

    fragC acc[8][4];
#pragma unroll
    for (int i = 0; i < 8; ++i)
#pragma unroll
        for (int j = 0; j < 4; ++j) { acc[i][j][0]=0.f; acc[i][j][1]=0.f; acc[i][j][2]=0.f; acc[i][j][3]=0.f; }

    for (int k0 = 0; k0 < 512; k0 += 64) {
#pragma unroll
        for (int i = 0; i < 4; ++i) {
            int ca = wv * 4 + i;
            GLD_LDS(Ag + (size_t)(ca * 8 + srow) * 512 + k0 + scol, &S[ca * 512]);
        }
#pragma unroll
        for (int i = 0; i < 8; ++i) {
            int cb = wv * 8 + i;
            int jl = cb * 8 + srow;                       // 0..255 local j
            int rg = hc * 128 + jl + ((jl & 128) ? 384 : 0);  // q rows / k rows (+512)
            GLD_LDS(wq + (size_t)rg * 512 + k0 + scol, &Bls[cb * 512]);
        }
        __syncthreads();
#pragma unroll
        for (int kk = 0; kk < 64; kk += 32) {
            int g = (kk >> 3) + (ln >> 4);
            fragAB bf[4];
#pragma unroll
            for (int nt = 0; nt < 4; ++nt) bf[nt] = ldfrag(Bls, wv * 64 + nt * 16 + (ln & 15), g);
#pragma unroll
            for (int mt = 0; mt < 8; ++mt) {
                fragAB a = ldfrag(S, mt * 16 + (ln & 15), g);
#pragma unroll
                for (int nt = 0; nt < 4; ++nt)
                    acc[mt][nt] = __builtin_amdgcn_mfma_f32_16x16x32_bf16(a, bf[nt], acc[mt][nt], 0, 0, 0);
            }
        }
        __syncthreads();
    }

    // bias + relu + pack -> transposed LDS tile (waves 0,1 -> Qt; 2,3 -> Kt)
#pragma unroll
    for (int nt = 0; nt < 4; ++nt) {
        int chl = (wv & 1) * 64 + nt * 16 + (ln & 15);    // 0..127 within q/k half
        float bias = bqkv[hc * 128 + chl + (isK ? 512 : 0)];
#pragma unroll
        for (int mt = 0; mt < 8; ++mt) {
            int nb = mt * 16 + (ln >> 4) * 4;
            float r0 = acc[mt][nt][0] + bias; r0 = r0 > 0.f ? r0 : 0.f;
            float r1 = acc[mt][nt][1] + bias; r1 = r1 > 0.f ? r1 : 0.f;
            float r2 = acc[mt][nt][2] + bias; r2 = r2 > 0.f ? r2 : 0.f;
            float r3 = acc[mt][nt][3] + bias; r3 = r3 > 0.f ? r3 : 0.f;
            uint2 pk;
            pk.x = f2bf(r0) | ((unsigned)f2bf(r1) << 16);
            pk.y = f2bf(r2) | ((unsigned)f2bf(r3) << 16);
            int g = nb >> 3, o = nb & 7;                  // o in {0,4}
            *(uint2*)&T[tidx(chl, g) + o] = pk;
        }
    }
    __syncthreads();

    // kq partial: wave wm -> head hc*2+wm, wn -> d-half. K-loop over n=128.
    // (r4 MFMA order; packed bf16 stores in lane-linear layout.)
    {
        const int wm = wv >> 1, wn = wv & 1;
        fragC ak[4][2];
#pragma unroll
        for (int i = 0; i < 4; ++i)
#pragma unroll
            for (int j = 0; j < 2; ++j) { ak[i][j][0]=0.f; ak[i][j][1]=0.f; ak[i][j][2]=0.f; ak[i][j][3]=0.f; }
        const int dh = wn * 32;
#pragma unroll
        for (int kk = 0; kk < 128; kk += 32) {
            int g = (kk >> 3) + (ln >> 4);
            fragAB bq[2];
#pragma unroll
            for (int dt = 0; dt < 2; ++dt)
                bq[dt] = *(const fragAB*)&Qt[tidx(wm * 64 + dh + dt * 16 + (ln & 15), g)];
#pragma unroll
            for (int mt = 0; mt < 4; ++mt) {
                fragAB a = *(const fragAB*)&Kt[tidx(wm * 64 + mt * 16 + (ln & 15), g)];
#pragma unroll
                for (int dt = 0; dt < 2; ++dt)
                    ak[mt][dt] = __builtin_amdgcn_mfma_f32_16x16x32_bf16(a, bq[dt], ak[mt][dt], 0, 0, 0);
            }
        }
        unsigned short* pb = partb + ((size_t)((b * 8 + hc * 2 + wm) * 128 + bx)) * 4096
                           + wn * 2048 + ln * 4;
#pragma unroll
        for (int mt = 0; mt < 4; ++mt)
#pragma unroll
            for (int dt = 0; dt < 2; ++dt) {
                uint2 pk;
                pk.x = f2bf(ak[mt][dt][0]) | ((unsigned)f2bf(ak[mt][dt][1]) << 16);
                pk.y = f2bf(ak[mt][dt][2]) | ((unsigned)f2bf(ak[mt][dt][3]) << 16);
                *(uint2*)&pb[dt * 1024 + mt * 256] = pk;
            }
    }
}

// ---------------- reduce partials: kq[bh][c*64+d] = sum over 128 n-blocks ----------------
// partb lane-linear layout: off = wn*2048 + dt*1024 + mt*256 + ln*4 + r holds
// kq[c = mt*16+(ln>>4)*4+r][d = wn*32+dt*16+(ln&15)].
__global__ __launch_bounds__(256) void reduce_kq(const unsigned short* __restrict__ partb,
                                                 float* __restrict__ kq) {
    const int tid = blockIdx.x * 256 + threadIdx.x;   // 0..32767
    const int bh  = tid >> 10;                        // 0..31
    const int s   = tid & 1023;                       // uint2 slot (4 bf16)
    const int off = s * 4;
    const unsigned short* p = partb + (size_t)bh * 128 * 4096 + off;
    float s0 = 0.f, s1 = 0.f, s2 = 0.f, s3 = 0.f;
#pragma unroll 4
    for (int blk = 0; blk < 128; ++blk) {
        uint2 v = *(const uint2*)(p + (size_t)blk * 4096);
        s0 += bf2f(v.x & 0xffffu); s1 += bf2f(v.x >> 16);
        s2 += bf2f(v.y & 0xffffu); s3 += bf2f(v.y >> 16);
    }
    const int wn = off >> 11, dt = (off >> 10) & 1, mt = (off >> 8) & 3, ln = (off >> 2) & 63;
    const int d  = wn * 32 + dt * 16 + (ln & 15);
    const int c0 = mt * 16 + (ln >> 4) * 4;
    float* o = &kq[(size_t)bh * 4096 + d];
    o[(c0 + 0) * 64] = s0;
    o[(c0 + 1) * 64] = s1;
    o[(c0 + 2) * 64] = s2;
    o[(c0 + 3) * 64] = s3;
}

// ---------------- fused w2+w3: grid (jc 16, cq 4, b 4) = 256 blocks ----------------
// Phase A (all blocks, redundant per cq): build W2loc[32 j][512 ch] bf16 in LDS
// from kq (r5's proven code); cq==0 also stores full bias2[j] (no atomics).
// Phase B: W3[b, j0..+32, cq*128..+128] = wvT . W2loc^T with wvT staged via
// GLD_LDS (fixes r5's scattered global gathers). W2 never touches HBM.
__global__ __launch_bounds__(256) void w2w3(
    const float* __restrict__ kq, const float* __restrict__ wout,
    const float* __restrict__ bqkv, const unsigned short* __restrict__ wvT,
    unsigned short* __restrict__ W3, float* __restrict__ b2a) {
    __shared__ float slab[64 * 65];            // [c'][d] padded
    __shared__ float p4[4 * 64];
    __shared__ float rnorm[64];
    __shared__ float wsc[32 * 65];             // [jl][d] padded
    __shared__ unsigned short W2loc[32 * 520]; // [jl][ch], pad 8 shorts (16B-aligned rows)
    __shared__ unsigned short Als[128 * 64];   // wvT tile staging (swizzled)
    const int jc = blockIdx.x;   // j0 = jc*32
    const int cq = blockIdx.y;   // c0 = cq*128
    const int b  = blockIdx.z;
    const int t  = threadIdx.x;
    const int jl = t >> 3, cg = (t & 7) * 8;
    float pacc = 0.f;

    for (int h = 0; h < 8; ++h) {
        const float* kqb = kq + ((size_t)(b * 8 + h)) * 4096;
#pragma unroll
        for (int i = 0; i < 4; ++i) {
            int e = t * 16 + i * 4;
            float4 v = *(const float4*)&kqb[e];
            float* r = &slab[(e >> 6) * 65 + (e & 63)];
            r[0] = v.x; r[1] = v.y; r[2] = v.z; r[3] = v.w;
        }
        __syncthreads();
        {
            int d = t & 63, cqq = t >> 6;
            float s = 0.f;
            for (int c = cqq * 16; c < cqq * 16 + 16; ++c) s += slab[c * 65 + d];
            p4[cqq * 64 + d] = s;
        }
        __syncthreads();
        if (t < 64) rnorm[t] = 1.0f / (p4[t] + p4[64 + t] + p4[128 + t] + p4[192 + t] + EPSV);
        __syncthreads();
        {
            const float* wrow = &wout[((size_t)(jc * 32 + jl)) * 512 + h];
#pragma unroll
            for (int i = 0; i < 8; ++i) {
                int d = (t & 7) * 8 + i;
                wsc[jl * 65 + d] = wrow[d * 8] * rnorm[d];
            }
        }
        __syncthreads();
        {
            float a[8] = {0.f, 0.f, 0.f, 0.f, 0.f, 0.f, 0.f, 0.f};
            for (int d = 0; d < 64; ++d) {
                float w = wsc[jl * 65 + d];
#pragma unroll
                for (int i = 0; i < 8; ++i) a[i] += w * slab[(cg + i) * 65 + d];
            }
            uint4 pk;
            pk.x = f2bf(a[0]) | ((unsigned)f2bf(a[1]) << 16);
            pk.y = f2bf(a[2]) | ((unsigned)f2bf(a[3]) << 16);
            pk.z = f2bf(a[4]) | ((unsigned)f2bf(a[5]) << 16);
            pk.w = f2bf(a[6]) | ((unsigned)f2bf(a[7]) << 16);
            *(uint4*)&W2loc[jl * 520 + h * 64 + cg] = pk;
            const float* bv = &bqkv[1024 + h * 64 + cg];
#pragma unroll
            for (int i = 0; i < 8; ++i) pacc += a[i] * bv[i];
        }
        __syncthreads();   // slab reused next h
    }

    // bias2 (cq==0 only): reduce pacc over the 8 threads of each jl, plain store.
    if (cq == 0) {
        float p = pacc;
        p += __shfl_down(p, 4, 64);
        p += __shfl_down(p, 2, 64);
        p += __shfl_down(p, 1, 64);
        if ((t & 7) == 0) b2a[b * 512 + jc * 32 + jl] = p;
    }
    __syncthreads();

    // Phase B: W3[b][j][c] = sum_ch wvT[c][ch] * W2loc[j_local][ch]
    {
        const int wv = t >> 6, ln = t & 63;
        const int mw = wv * 32;                       // 4 waves x 32 c = 128
        const int srow = ln >> 3;
        const int scol = ((ln & 7) ^ srow) << 3;
        const unsigned short* Ag = wvT + (size_t)(cq * 128) * 512;
        fragC acc[2][2];
#pragma unroll
        for (int i = 0; i < 2; ++i)
#pragma unroll
            for (int j = 0; j < 2; ++j) { acc[i][j][0]=0.f; acc[i][j][1]=0.f; acc[i][j][2]=0.f; acc[i][j][3]=0.f; }

        for (int k0 = 0; k0 < 512; k0 += 64) {
#pragma unroll
            for (int i = 0; i < 4; ++i) {
                int chunk = wv * 4 + i;
                int row = chunk * 8 + srow;
                GLD_LDS(Ag + (size_t)row * 512 + k0 + scol, &Als[chunk * 512]);
            }
            __syncthreads();
#pragma unroll
            for (int kk = 0; kk < 64; kk += 32) {
                int g = (kk >> 3) + (ln >> 4);
                int koff = k0 + kk + (ln >> 4) * 8;
                fragAB a[2], bf[2];
#pragma unroll
                for (int mt = 0; mt < 2; ++mt) a[mt] = ldfrag(Als, mw + mt * 16 + (ln & 15), g);
#pragma unroll
                for (int nt = 0; nt < 2; ++nt)
                    bf[nt] = *(const fragAB*)&W2loc[(nt * 16 + (ln & 15)) * 520 + koff];
#pragma unroll
                for (int mt = 0; mt < 2; ++mt)
#pragma unroll
                    for (int nt = 0; nt < 2; ++nt)
                        acc[mt][nt] = __builtin_amdgcn_mfma_f32_16x16x32_bf16(a[mt], bf[nt], acc[mt][nt], 0, 0, 0);
            }
            __syncthreads();
        }

#pragma unroll
        for (int mt = 0; mt < 2; ++mt)
#pragma unroll
            for (int nt = 0; nt < 2; ++nt) {
                int c = cq * 128 + mw + mt * 16 + (ln >> 4) * 4;
                int j = jc * 32 + nt * 16 + (ln & 15);
                uint2 pk;
                pk.x = f2bf(acc[mt][nt][0]) | ((unsigned)f2bf(acc[mt][nt][1]) << 16);
                pk.y = f2bf(acc[mt][nt][2]) | ((unsigned)f2bf(acc[mt][nt][3]) << 16);
                *(uint2*)&W3[((size_t)(b * 512 + j)) * 512 + c] = pk;
            }
    }
}

// ---------------- out GEMM: 128n x 256j blocks, wave tile 128x64 ----------------
__global__ __launch_bounds__(256, 2) void gemm_out(
    const unsigned short* __restrict__ xt, const unsigned short* __restrict__ W3,
    const float* __restrict__ b2a, const float* __restrict__ bout,
    float* __restrict__ out) {
    __shared__ unsigned short Als[128 * 64];
    __shared__ unsigned short Bls[256 * 64];
    const int b  = blockIdx.z;
    const int n0 = blockIdx.x * 128;
    const int j0 = blockIdx.y * 256;
    const int t  = threadIdx.x;
    const int wv = t >> 6, ln = t & 63;
    const unsigned short* Ag = xt + (size_t)(b * NSP + n0) * 512;
    const unsigned short* Bg = W3 + ((size_t)(b * 512 + j0)) * 512;

    fragC acc[8][4];
#pragma unroll
    for (int i = 0; i < 8; ++i)
#pragma unroll
        for (int j = 0; j < 4; ++j) { acc[i][j][0]=0.f; acc[i][j][1]=0.f; acc[i][j][2]=0.f; acc[i][j][3]=0.f; }

    const int srow = ln >> 3;
    const int scol = ((ln & 7) ^ srow) << 3;

    for (int k0 = 0; k0 < 512; k0 += 64) {
#pragma unroll
        for (int i = 0; i < 4; ++i) {
            int ca = wv * 4 + i;
            GLD_LDS(Ag + (size_t)(ca * 8 + srow) * 512 + k0 + scol, &Als[ca * 512]);
        }
#pragma unroll
        for (int i = 0; i < 8; ++i) {
            int cb = wv * 8 + i;
            GLD_LDS(Bg + (size_t)(cb * 8 + srow) * 512 + k0 + scol, &Bls[cb * 512]);
        }
        __syncthreads();
#pragma unroll
        for (int kk = 0; kk < 64; kk += 32) {
            int g = (kk >> 3) + (ln >> 4);
            fragAB bf[4];
#pragma unroll
            for (int nt = 0; nt < 4; ++nt) bf[nt] = ldfrag(Bls, wv * 64 + nt * 16 + (ln & 15), g);
#pragma unroll
            for (int mt = 0; mt < 8; ++mt) {
                fragAB a = ldfrag(Als, mt * 16 + (ln & 15), g);
#pragma unroll
                for (int nt = 0; nt < 4; ++nt)
                    acc[mt][nt] = __builtin_amdgcn_mfma_f32_16x16x32_bf16(a, bf[nt], acc[mt][nt], 0, 0, 0);
            }
        }
        __syncthreads();
    }

#pragma unroll
    for (int nt = 0; nt < 4; ++nt) {
        int j = j0 + wv * 64 + nt * 16 + (ln & 15);
        float bias = bout[j] + b2a[b * 512 + j];
#pragma unroll
        for (int mt = 0; mt < 8; ++mt) {
            int n = n0 + mt * 16 + (ln >> 4) * 4;
            float4 v;
            v.x = acc[mt][nt][0] + bias;
            v.y = acc[mt][nt][1] + bias;
            v.z = acc[mt][nt][2] + bias;
            v.w = acc[mt][nt][3] + bias;
            *(float4*)&out[((size_t)(b * 512 + j)) * NSP + n] = v;
        }
    }
}

extern "C" void kernel_launch(void* const* d_in, const int* in_sizes, int n_in,
                              void* d_out, int out_size, void* d_ws, size_t ws_size,
                              hipStream_t stream) {
    const float* x    = (const float*)d_in[0];
    const float* wqkv = (const float*)d_in[1];
    const float* bqkv = (const float*)d_in[2];
    const float* wout = (const float*)d_in[3];
    const float* bout = (const float*)d_in[4];
    float* out = (float*)d_out;

    char* p = (char*)d_ws;
    unsigned short* xt    = (unsigned short*)p; p += (size_t)BATCH * NSP * 512 * 2;   // 64 MB
    unsigned short* wqb   = (unsigned short*)p; p += (size_t)1024 * 512 * 2;          // 1 MB
    unsigned short* wvT   = (unsigned short*)p; p += (size_t)512 * 512 * 2;           // 0.5 MB
    unsigned short* partb = (unsigned short*)p; p += (size_t)32 * 128 * 4096 * 2;     // 32 MB
    float*          kq    = (float*)p;          p += (size_t)BATCH * 32768 * 4;       // 512 KB
    float*          b2a   = (float*)p;          p += (size_t)BATCH * 512 * 4;         // 8 KB
    unsigned short* W3    = (unsigned short*)p; p += (size_t)BATCH * 512 * 512 * 2;   // 2 MB

    transpose_prep<<<dim3(8768), 256, 0, stream>>>(x, xt, wqkv, wqb, wvT);
    gemm_qk_kq<<<dim3(128, 4, BATCH), 256, 0, stream>>>(xt, wqb, bqkv, partb);
    reduce_kq<<<dim3(128), 256, 0, stream>>>(partb, kq);
    w2w3<<<dim3(16, 4, BATCH), 256, 0, stream>>>(kq, wout, bqkv, wvT, W3, b2a);
    gemm_out<<<dim3(128, 2, BATCH), 256, 0, stream>>>(xt, W3, b2a, bout, out);
}

// Round 9
// 386.189 us; speedup vs baseline: 1.0664x; 1.0664x over previous
//
#include <hip/hip_runtime.h>
#include <hip/hip_bf16.h>
#include <stdint.h>

#define NSP 16384   // 128*128 spatial
#define BATCH 4
#define EPSV 1e-6f

typedef __attribute__((ext_vector_type(8))) short fragAB;   // 8 bf16
typedef __attribute__((ext_vector_type(4))) float fragC;    // 4 fp32

__device__ __forceinline__ unsigned short f2bf(float f) {
    union { float f; unsigned u; } un; un.f = f;
    unsigned r = un.u + 0x7fffu + ((un.u >> 16) & 1u);   // RNE
    return (unsigned short)(r >> 16);
}

__device__ __forceinline__ float bf2f(unsigned u) {
    union { unsigned u; float f; } x; x.u = u << 16; return x.f;
}

#define GLD_LDS(g, l) __builtin_amdgcn_global_load_lds( \
    (const __attribute__((address_space(1))) void*)(g), \
    (__attribute__((address_space(3))) void*)(l), 16, 0, 0)

// XOR-swizzled fragment read: element (row m, colgroup g) at
// (m>>3)*512 + (m&7)*64 + ((g ^ (m&7))*8); matches global_load_lds lane slots.
__device__ __forceinline__ fragAB ldfrag(const unsigned short* ls, int m, int g) {
    return *(const fragAB*)&ls[((m >> 3) << 9) + ((m & 7) << 6) + ((g ^ (m & 7)) << 3)];
}

// Transposed q/k chunk tile [ch][n=128] bf16, XOR-swizzled: group g of row ch
// lives at slot (g ^ (ch&7)). Row stride 128 shorts (256 B).
__device__ __forceinline__ int tidx(int ch, int g) {
    return (ch << 7) + ((g ^ (ch & 7)) << 3);
}

// ---------------- fused: x transpose (blocks 0..8191) + weight prep (8192..8767) ----------------
__global__ __launch_bounds__(256) void transpose_prep(
    const float* __restrict__ x, unsigned short* __restrict__ xt,
    const float* __restrict__ wqkv, unsigned short* __restrict__ wqb,
    unsigned short* __restrict__ wvT) {
    __shared__ float lds[64 * 65];
    const int blk = blockIdx.x;
    const int t   = threadIdx.x;
    if (blk < 8192) {
        // ---- transpose_x: x (B,C,N) fp32 -> xt (B,N,C) bf16 ----
        const int b  = blk >> 11;
        const int c0 = ((blk >> 8) & 7) * 64;
        const int n0 = (blk & 255) * 64;
        const int nl = (t & 15) * 4;
        const int cl = t >> 4;
#pragma unroll
        for (int i = 0; i < 4; ++i) {
            int c = cl + i * 16;
            float4 v = *(const float4*)&x[((size_t)(b * 512 + c0 + c)) * NSP + n0 + nl];
            float* row = &lds[c * 65 + nl];
            row[0] = v.x; row[1] = v.y; row[2] = v.z; row[3] = v.w;
        }
        __syncthreads();
#pragma unroll
        for (int i = 0; i < 2; ++i) {
            int ch = t + i * 256;      // 0..511
            int n  = ch >> 3;
            int co = (ch & 7) * 8;
            unsigned v0, v1, v2, v3;
            v0 = f2bf(lds[(co + 0) * 65 + n]) | ((unsigned)f2bf(lds[(co + 1) * 65 + n]) << 16);
            v1 = f2bf(lds[(co + 2) * 65 + n]) | ((unsigned)f2bf(lds[(co + 3) * 65 + n]) << 16);
            v2 = f2bf(lds[(co + 4) * 65 + n]) | ((unsigned)f2bf(lds[(co + 5) * 65 + n]) << 16);
            v3 = f2bf(lds[(co + 6) * 65 + n]) | ((unsigned)f2bf(lds[(co + 7) * 65 + n]) << 16);
            uint4 pk; pk.x = v0; pk.y = v1; pk.z = v2; pk.w = v3;
            *(uint4*)&xt[((size_t)(b * NSP + n0 + n)) * 512 + c0 + co] = pk;
        }
        return;
    }
    const int pblk = blk - 8192;
    if (pblk < 512) {
        // ---- wqkv rows 0..1023 -> bf16 ----
        int i = (pblk * 256 + t) * 4;
        float4 v = *(const float4*)&wqkv[i];
        uint2 pk;
        pk.x = f2bf(v.x) | ((unsigned)f2bf(v.y) << 16);
        pk.y = f2bf(v.z) | ((unsigned)f2bf(v.w) << 16);
        *(uint2*)&wqb[i] = pk;
        return;
    }
    // ---- wv rows -> wvT (transposed, bf16) ----
    const int c0  = ((pblk - 512) & 7) * 64;
    const int ch0 = ((pblk - 512) >> 3) * 64;
    const int cl  = (t & 15) * 4;
    const int rl  = t >> 4;
#pragma unroll
    for (int i = 0; i < 4; ++i) {
        int r = rl + i * 16;   // ch row
        float4 v = *(const float4*)&wqkv[((size_t)(1024 + ch0 + r)) * 512 + c0 + cl];
        float* row = &lds[r * 65 + cl];
        row[0] = v.x; row[1] = v.y; row[2] = v.z; row[3] = v.w;
    }
    __syncthreads();
#pragma unroll
    for (int i = 0; i < 2; ++i) {
        int idx = t + i * 256;
        int c = idx >> 3;
        int g = (idx & 7) * 8;
        unsigned v0, v1, v2, v3;
        v0 = f2bf(lds[(g + 0) * 65 + c]) | ((unsigned)f2bf(lds[(g + 1) * 65 + c]) << 16);
        v1 = f2bf(lds[(g + 2) * 65 + c]) | ((unsigned)f2bf(lds[(g + 3) * 65 + c]) << 16);
        v2 = f2bf(lds[(g + 4) * 65 + c]) | ((unsigned)f2bf(lds[(g + 5) * 65 + c]) << 16);
        v3 = f2bf(lds[(g + 6) * 65 + c]) | ((unsigned)f2bf(lds[(g + 7) * 65 + c]) << 16);
        uint4 pk; pk.x = v0; pk.y = v1; pk.z = v2; pk.w = v3;
        *(uint4*)&wvT[((size_t)(c0 + c)) * 512 + ch0 + g] = pk;
    }
}

// ---------------- fused q/k GEMM + kq partial reduction (r8 -- 80us, proven) ----------------
// GEMM phase = r4 non-spilling shape. kq tail: r4's MFMA order + bf16 packed
// lane-linear stores. Slot map: wn*2048 + dt*1024 + mt*256 + ln*4 + r holds
// kq[c = mt*16+(ln>>4)*4+r][d = wn*32+dt*16+(ln&15)].
__global__ __launch_bounds__(256, 2) void gemm_qk_kq(
    const unsigned short* __restrict__ xt, const unsigned short* __restrict__ wq,
    const float* __restrict__ bqkv, unsigned short* __restrict__ partb) {
    __shared__ unsigned short S[(128 + 256) * 64];   // Als @0 (16KB), Bls @8192 (32KB)
    __shared__ unsigned short Qt[128 * 128];          // 32KB
    unsigned short* Bls = &S[8192];
    unsigned short* Kt  = &S[0];                      // alias: dead during staging, live after

    const int b  = blockIdx.z;
    const int hc = blockIdx.y;                        // head-pair chunk 0..3
    const int bx = blockIdx.x;
    const int n0 = bx * 128;
    const int t  = threadIdx.x;
    const int wv = t >> 6, ln = t & 63;
    const unsigned short* Ag = xt + (size_t)(b * NSP + n0) * 512;
    const int srow = ln >> 3;
    const int scol = ((ln & 7) ^ srow) << 3;
    const int isK = wv >> 1;                          // waves 2,3 -> k-channels
    unsigned short* T = isK ? Kt : Qt;

    fragC acc[8][4];
#pragma unroll
    for (int i = 0; i < 8; ++i)
#pragma unroll
        for (int j = 0; j < 4; ++j) { acc[i][j][0]=0.f; acc[i][j][1]=0.f; acc[i][j][2]=0.f; acc[i][j][3]=0.f; }

    for (int k0 = 0; k0 < 512; k0 += 64) {
#pragma unroll
        for (int i = 0; i < 4; ++i) {
            int ca = wv * 4 + i;
            GLD_LDS(Ag + (size_t)(ca * 8 + srow) * 512 + k0 + scol, &S[ca * 512]);
        }
#pragma unroll
        for (int i = 0; i < 8; ++i) {
            int cb = wv * 8 + i;
            int jl = cb * 8 + srow;                       // 0..255 local j
            int rg = hc * 128 + jl + ((jl & 128) ? 384 : 0);  // q rows / k rows (+512)
            GLD_LDS(wq + (size_t)rg * 512 + k0 + scol, &Bls[cb * 512]);
        }
        __syncthreads();
#pragma unroll
        for (int kk = 0; kk < 64; kk += 32) {
            int g = (kk >> 3) + (ln >> 4);
            fragAB bf[4];
#pragma unroll
            for (int nt = 0; nt < 4; ++nt) bf[nt] = ldfrag(Bls, wv * 64 + nt * 16 + (ln & 15), g);
#pragma unroll
            for (int mt = 0; mt < 8; ++mt) {
                fragAB a = ldfrag(S, mt * 16 + (ln & 15), g);
#pragma unroll
                for (int nt = 0; nt < 4; ++nt)
                    acc[mt][nt] = __builtin_amdgcn_mfma_f32_16x16x32_bf16(a, bf[nt], acc[mt][nt], 0, 0, 0);
            }
        }
        __syncthreads();
    }

    // bias + relu + pack -> transposed LDS tile (waves 0,1 -> Qt; 2,3 -> Kt)
#pragma unroll
    for (int nt = 0; nt < 4; ++nt) {
        int chl = (wv & 1) * 64 + nt * 16 + (ln & 15);    // 0..127 within q/k half
        float bias = bqkv[hc * 128 + chl + (isK ? 512 : 0)];
#pragma unroll
        for (int mt = 0; mt < 8; ++mt) {
            int nb = mt * 16 + (ln >> 4) * 4;
            float r0 = acc[mt][nt][0] + bias; r0 = r0 > 0.f ? r0 : 0.f;
            float r1 = acc[mt][nt][1] + bias; r1 = r1 > 0.f ? r1 : 0.f;
            float r2 = acc[mt][nt][2] + bias; r2 = r2 > 0.f ? r2 : 0.f;
            float r3 = acc[mt][nt][3] + bias; r3 = r3 > 0.f ? r3 : 0.f;
            uint2 pk;
            pk.x = f2bf(r0) | ((unsigned)f2bf(r1) << 16);
            pk.y = f2bf(r2) | ((unsigned)f2bf(r3) << 16);
            int g = nb >> 3, o = nb & 7;                  // o in {0,4}
            *(uint2*)&T[tidx(chl, g) + o] = pk;
        }
    }
    __syncthreads();

    // kq partial: wave wm -> head hc*2+wm, wn -> d-half. K-loop over n=128.
    {
        const int wm = wv >> 1, wn = wv & 1;
        fragC ak[4][2];
#pragma unroll
        for (int i = 0; i < 4; ++i)
#pragma unroll
            for (int j = 0; j < 2; ++j) { ak[i][j][0]=0.f; ak[i][j][1]=0.f; ak[i][j][2]=0.f; ak[i][j][3]=0.f; }
        const int dh = wn * 32;
#pragma unroll
        for (int kk = 0; kk < 128; kk += 32) {
            int g = (kk >> 3) + (ln >> 4);
            fragAB bq[2];
#pragma unroll
            for (int dt = 0; dt < 2; ++dt)
                bq[dt] = *(const fragAB*)&Qt[tidx(wm * 64 + dh + dt * 16 + (ln & 15), g)];
#pragma unroll
            for (int mt = 0; mt < 4; ++mt) {
                fragAB a = *(const fragAB*)&Kt[tidx(wm * 64 + mt * 16 + (ln & 15), g)];
#pragma unroll
                for (int dt = 0; dt < 2; ++dt)
                    ak[mt][dt] = __builtin_amdgcn_mfma_f32_16x16x32_bf16(a, bq[dt], ak[mt][dt], 0, 0, 0);
            }
        }
        unsigned short* pb = partb + ((size_t)((b * 8 + hc * 2 + wm) * 128 + bx)) * 4096
                           + wn * 2048 + ln * 4;
#pragma unroll
        for (int mt = 0; mt < 4; ++mt)
#pragma unroll
            for (int dt = 0; dt < 2; ++dt) {
                uint2 pk;
                pk.x = f2bf(ak[mt][dt][0]) | ((unsigned)f2bf(ak[mt][dt][1]) << 16);
                pk.y = f2bf(ak[mt][dt][2]) | ((unsigned)f2bf(ak[mt][dt][3]) << 16);
                *(uint2*)&pb[dt * 1024 + mt * 256] = pk;
            }
    }
}

// ---------------- reduce partials: kq[bh][c*64+d] = sum over 128 n-blocks ----------------
__global__ __launch_bounds__(256) void reduce_kq(const unsigned short* __restrict__ partb,
                                                 float* __restrict__ kq) {
    const int tid = blockIdx.x * 256 + threadIdx.x;   // 0..32767
    const int bh  = tid >> 10;                        // 0..31
    const int s   = tid & 1023;                       // uint2 slot (4 bf16)
    const int off = s * 4;
    const unsigned short* p = partb + (size_t)bh * 128 * 4096 + off;
    float s0 = 0.f, s1 = 0.f, s2 = 0.f, s3 = 0.f;
#pragma unroll 4
    for (int blk = 0; blk < 128; ++blk) {
        uint2 v = *(const uint2*)(p + (size_t)blk * 4096);
        s0 += bf2f(v.x & 0xffffu); s1 += bf2f(v.x >> 16);
        s2 += bf2f(v.y & 0xffffu); s3 += bf2f(v.y >> 16);
    }
    const int wn = off >> 11, dt = (off >> 10) & 1, mt = (off >> 8) & 3, ln = (off >> 2) & 63;
    const int d  = wn * 32 + dt * 16 + (ln & 15);
    const int c0 = mt * 16 + (ln >> 4) * 4;
    float* o = &kq[(size_t)bh * 4096 + d];
    o[(c0 + 0) * 64] = s0;
    o[(c0 + 1) * 64] = s1;
    o[(c0 + 2) * 64] = s2;
    o[(c0 + 3) * 64] = s3;
}

// ---------------- W2 via LDS slab: block = (j-chunk 32, h, b) -- r7, proven ----------------
// bias2 partial per head stored race-free to b2ap[(b*8+h)*512 + j] (no atomics).
__global__ __launch_bounds__(256) void w2_kernel(
    const float* __restrict__ kq, const float* __restrict__ wout,
    const float* __restrict__ bqkv,
    unsigned short* __restrict__ W2, float* __restrict__ b2ap) {
    __shared__ float slab[64 * 65];   // [c][d] padded
    __shared__ float part[4 * 64];
    __shared__ float rnorm[64];
    __shared__ float wsc[32 * 65];    // [jl][d] padded
    const int jc = blockIdx.x;   // j0 = jc*32
    const int h  = blockIdx.y;
    const int b  = blockIdx.z;
    const int t  = threadIdx.x;
    const float* kqb = kq + ((size_t)(b * 8 + h)) * 4096;
#pragma unroll
    for (int i = 0; i < 4; ++i) {
        int e = t * 16 + i * 4;
        float4 v = *(const float4*)&kqb[e];
        float* r = &slab[(e >> 6) * 65 + (e & 63)];
        r[0] = v.x; r[1] = v.y; r[2] = v.z; r[3] = v.w;
    }
    __syncthreads();
    {
        int d = t & 63, cq = t >> 6;
        float s = 0.f;
        for (int c = cq * 16; c < cq * 16 + 16; ++c) s += slab[c * 65 + d];
        part[cq * 64 + d] = s;
    }
    __syncthreads();
    if (t < 64) rnorm[t] = 1.0f / (part[t] + part[64 + t] + part[128 + t] + part[192 + t] + EPSV);
    __syncthreads();
    {
        int jl = t >> 3;
        const float* wrow = &wout[((size_t)(jc * 32 + jl)) * 512 + h];
#pragma unroll
        for (int i = 0; i < 8; ++i) {
            int d = (t & 7) * 8 + i;
            wsc[jl * 65 + d] = wrow[d * 8] * rnorm[d];
        }
    }
    __syncthreads();
    {
        int jl = t >> 3, cg = (t & 7) * 8;
        int j  = jc * 32 + jl;
        float a[8] = {0.f, 0.f, 0.f, 0.f, 0.f, 0.f, 0.f, 0.f};
        for (int d = 0; d < 64; ++d) {
            float w = wsc[jl * 65 + d];
#pragma unroll
            for (int i = 0; i < 8; ++i) a[i] += w * slab[(cg + i) * 65 + d];
        }
        uint4 pk;
        pk.x = f2bf(a[0]) | ((unsigned)f2bf(a[1]) << 16);
        pk.y = f2bf(a[2]) | ((unsigned)f2bf(a[3]) << 16);
        pk.z = f2bf(a[4]) | ((unsigned)f2bf(a[5]) << 16);
        pk.w = f2bf(a[6]) | ((unsigned)f2bf(a[7]) << 16);
        *(uint4*)&W2[((size_t)(b * 512 + j)) * 512 + h * 64 + cg] = pk;
        const float* bv = &bqkv[1024 + h * 64 + cg];
        float p = 0.f;
#pragma unroll
        for (int i = 0; i < 8; ++i) p += a[i] * bv[i];
        p += __shfl_down(p, 4, 64);
        p += __shfl_down(p, 2, 64);
        p += __shfl_down(p, 1, 64);
        if ((t & 7) == 0) b2ap[((size_t)(b * 8 + h) << 9) + j] = p;
    }
}

// ---------------- W3[b,j,c] = sum_ch wvT[c,ch]*W2[b,j,ch] -- r7 64x64 tiles, proven ----------------
__global__ __launch_bounds__(256) void w3_kernel(
    const unsigned short* __restrict__ wvT, const unsigned short* __restrict__ W2,
    unsigned short* __restrict__ W3) {
    __shared__ unsigned short Als[64 * 64];
    __shared__ unsigned short Bls[64 * 64];
    const int b  = blockIdx.z;
    const int m0 = blockIdx.x * 64;    // c
    const int n0 = blockIdx.y * 64;    // j
    const int t  = threadIdx.x;
    const int wv = t >> 6, ln = t & 63;
    const unsigned short* Ag = wvT + (size_t)m0 * 512;
    const unsigned short* Bg = W2 + ((size_t)(b * 512 + n0)) * 512;

    fragC acc[2][2];
#pragma unroll
    for (int i = 0; i < 2; ++i)
#pragma unroll
        for (int j = 0; j < 2; ++j) { acc[i][j][0]=0.f; acc[i][j][1]=0.f; acc[i][j][2]=0.f; acc[i][j][3]=0.f; }

    const int mw = (wv >> 1) * 32, nw = (wv & 1) * 32;
    const int srow = ln >> 3;
    const int scol = ((ln & 7) ^ srow) << 3;

    for (int k0 = 0; k0 < 512; k0 += 64) {
#pragma unroll
        for (int i = 0; i < 2; ++i) {
            int chunk = wv * 2 + i;
            int row = chunk * 8 + srow;
            GLD_LDS(Ag + (size_t)row * 512 + k0 + scol, &Als[chunk * 512]);
            GLD_LDS(Bg + (size_t)row * 512 + k0 + scol, &Bls[chunk * 512]);
        }
        __syncthreads();
#pragma unroll
        for (int kk = 0; kk < 64; kk += 32) {
            int g = (kk >> 3) + (ln >> 4);
            fragAB a[2], bf[2];
#pragma unroll
            for (int mt = 0; mt < 2; ++mt) a[mt]  = ldfrag(Als, mw + mt * 16 + (ln & 15), g);
#pragma unroll
            for (int nt = 0; nt < 2; ++nt) bf[nt] = ldfrag(Bls, nw + nt * 16 + (ln & 15), g);
#pragma unroll
            for (int mt = 0; mt < 2; ++mt)
#pragma unroll
                for (int nt = 0; nt < 2; ++nt)
                    acc[mt][nt] = __builtin_amdgcn_mfma_f32_16x16x32_bf16(a[mt], bf[nt], acc[mt][nt], 0, 0, 0);
        }
        __syncthreads();
    }

#pragma unroll
    for (int mt = 0; mt < 2; ++mt)
#pragma unroll
        for (int nt = 0; nt < 2; ++nt) {
            int c = m0 + mw + mt * 16 + (ln >> 4) * 4;
            int j = n0 + nw + nt * 16 + (ln & 15);
            uint2 pk;
            pk.x = f2bf(acc[mt][nt][0]) | ((unsigned)f2bf(acc[mt][nt][1]) << 16);
            pk.y = f2bf(acc[mt][nt][2]) | ((unsigned)f2bf(acc[mt][nt][3]) << 16);
            *(uint2*)&W3[((size_t)(b * 512 + j)) * 512 + c] = pk;
        }
}

// ---------------- out GEMM: 128n x 256j blocks, wave tile 128x64 ----------------
__global__ __launch_bounds__(256, 2) void gemm_out(
    const unsigned short* __restrict__ xt, const unsigned short* __restrict__ W3,
    const float* __restrict__ b2ap, const float* __restrict__ bout,
    float* __restrict__ out) {
    __shared__ unsigned short Als[128 * 64];
    __shared__ unsigned short Bls[256 * 64];
    const int b  = blockIdx.z;
    const int n0 = blockIdx.x * 128;
    const int j0 = blockIdx.y * 256;
    const int t  = threadIdx.x;
    const int wv = t >> 6, ln = t & 63;
    const unsigned short* Ag = xt + (size_t)(b * NSP + n0) * 512;
    const unsigned short* Bg = W3 + ((size_t)(b * 512 + j0)) * 512;

    fragC acc[8][4];
#pragma unroll
    for (int i = 0; i < 8; ++i)
#pragma unroll
        for (int j = 0; j < 4; ++j) { acc[i][j][0]=0.f; acc[i][j][1]=0.f; acc[i][j][2]=0.f; acc[i][j][3]=0.f; }

    const int srow = ln >> 3;
    const int scol = ((ln & 7) ^ srow) << 3;

    for (int k0 = 0; k0 < 512; k0 += 64) {
#pragma unroll
        for (int i = 0; i < 4; ++i) {
            int ca = wv * 4 + i;
            GLD_LDS(Ag + (size_t)(ca * 8 + srow) * 512 + k0 + scol, &Als[ca * 512]);
        }
#pragma unroll
        for (int i = 0; i < 8; ++i) {
            int cb = wv * 8 + i;
            GLD_LDS(Bg + (size_t)(cb * 8 + srow) * 512 + k0 + scol, &Bls[cb * 512]);
        }
        __syncthreads();
#pragma unroll
        for (int kk = 0; kk < 64; kk += 32) {
            int g = (kk >> 3) + (ln >> 4);
            fragAB bf[4];
#pragma unroll
            for (int nt = 0; nt < 4; ++nt) bf[nt] = ldfrag(Bls, wv * 64 + nt * 16 + (ln & 15), g);
#pragma unroll
            for (int mt = 0; mt < 8; ++mt) {
                fragAB a = ldfrag(Als, mt * 16 + (ln & 15), g);
#pragma unroll
                for (int nt = 0; nt < 4; ++nt)
                    acc[mt][nt] = __builtin_amdgcn_mfma_f32_16x16x32_bf16(a, bf[nt], acc[mt][nt], 0, 0, 0);
            }
        }
        __syncthreads();
    }

#pragma unroll
    for (int nt = 0; nt < 4; ++nt) {
        int j = j0 + wv * 64 + nt * 16 + (ln & 15);
        float bias = bout[j];
#pragma unroll
        for (int h = 0; h < 8; ++h) bias += b2ap[((size_t)(b * 8 + h) << 9) + j];
#pragma unroll
        for (int mt = 0; mt < 8; ++mt) {
            int n = n0 + mt * 16 + (ln >> 4) * 4;
            float4 v;
            v.x = acc[mt][nt][0] + bias;
            v.y = acc[mt][nt][1] + bias;
            v.z = acc[mt][nt][2] + bias;
            v.w = acc[mt][nt][3] + bias;
            *(float4*)&out[((size_t)(b * 512 + j)) * NSP + n] = v;
        }
    }
}

extern "C" void kernel_launch(void* const* d_in, const int* in_sizes, int n_in,
                              void* d_out, int out_size, void* d_ws, size_t ws_size,
                              hipStream_t stream) {
    const float* x    = (const float*)d_in[0];
    const float* wqkv = (const float*)d_in[1];
    const float* bqkv = (const float*)d_in[2];
    const float* wout = (const float*)d_in[3];
    const float* bout = (const float*)d_in[4];
    float* out = (float*)d_out;

    char* p = (char*)d_ws;
    unsigned short* xt    = (unsigned short*)p; p += (size_t)BATCH * NSP * 512 * 2;   // 64 MB
    unsigned short* wqb   = (unsigned short*)p; p += (size_t)1024 * 512 * 2;          // 1 MB
    unsigned short* wvT   = (unsigned short*)p; p += (size_t)512 * 512 * 2;           // 0.5 MB
    unsigned short* partb = (unsigned short*)p; p += (size_t)32 * 128 * 4096 * 2;     // 32 MB
    float*          kq    = (float*)p;          p += (size_t)BATCH * 32768 * 4;       // 512 KB
    float*          b2ap  = (float*)p;          p += (size_t)BATCH * 8 * 512 * 4;     // 64 KB
    unsigned short* W2    = (unsigned short*)p; p += (size_t)BATCH * 512 * 512 * 2;   // 2 MB
    unsigned short* W3    = (unsigned short*)p; p += (size_t)BATCH * 512 * 512 * 2;   // 2 MB

    transpose_prep<<<dim3(8768), 256, 0, stream>>>(x, xt, wqkv, wqb, wvT);
    gemm_qk_kq<<<dim3(128, 4, BATCH), 256, 0, stream>>>(xt, wqb, bqkv, partb);
    reduce_kq<<<dim3(128), 256, 0, stream>>>(partb, kq);
    w2_kernel<<<dim3(16, 8, BATCH), 256, 0, stream>>>(kq, wout, bqkv, W2, b2ap);
    w3_kernel<<<dim3(8, 8, BATCH), 256, 0, stream>>>(wvT, W2, W3);
    gemm_out<<<dim3(128, 2, BATCH), 256, 0, stream>>>(xt, W3, b2ap, bout, out);
}